// Round 17
// baseline (44.744 us; speedup 1.0000x reference)
//
#include <hip/hip_runtime.h>

// Depthwise cross-correlation, B*C = 32768 planes: x[32][32] (*) k[8][8] -> out[25][25].
// softmax(weight) sums to 1.0 -> output == correlation; weight unused.
//
// Round-13 structure (best passing, 43.8us): thread = (plane, ox), one output
// column (25 outputs); single packed-bf16 copy of x in LDS (RST=18, XP=592,
// plane shifts {0,12,8}); odd columns via v_alignbit (sh=(ox&1)*16); dot2
// inner loop; taps (32 packed dwords) register-resident.
// Round-17 change: BLOCK GRANULARITY. PPB 8->4, block 256->128. LDS/block
// 10048 B -> 15 blocks/CU (HW cap 16) = 30 waves/CU, vs r13's 8 blocks.
// More independent blocks per CU = statistical overlap of VMEM-staging and
// LDS-compute phases + narrower (2-wave) barriers. Layout/math unchanged.

#define NPLANES (128 * 256)
#define PPB 4
#define RST 18                      // row stride (dwords): 16 data + 2 pad
#define XP  592                     // plane stride: >= 576+max_shift(12), %4==0
#define KTB (PPB * XP)              // taps base (2368, %4==0)
#define KTS 36                      // taps plane stride
#define LDS_DW (KTB + PPB * KTS)    // 2512 dw = 10048 B -> 15 blocks/CU
#define OH 25
#define OW 25

__device__ __forceinline__ unsigned cvt_pk_bf16(float a, float b) {
    unsigned r;  // lo = bf16(a), hi = bf16(b)
    asm("v_cvt_pk_bf16_f32 %0, %1, %2" : "=v"(r) : "v"(a), "v"(b));
    return r;
}
__device__ __forceinline__ void dot2(float& acc, unsigned x2, unsigned k2) {
    asm("v_dot2_f32_bf16 %0, %1, %2, %0" : "+v"(acc) : "v"(x2), "v"(k2));
}
__device__ __forceinline__ unsigned alignb(unsigned hi, unsigned lo, unsigned sh) {
    unsigned r;  // ((hi:lo) >> sh)[31:0]; sh=0 -> lo
    asm("v_alignbit_b32 %0, %1, %2, %3" : "=v"(r) : "v"(hi), "v"(lo), "v"(sh));
    return r;
}

__device__ __forceinline__ int plane_shift(int pl) {
    const int m = pl % 3;           // bank de-correlation, even dwords
    return (m == 0) ? 0 : (m == 1) ? 12 : 8;
}

__global__ __launch_bounds__(128)
void dwxcorr_kernel(const float* __restrict__ x,
                    const float* __restrict__ kern,
                    float* __restrict__ out) {
    __shared__ unsigned ldsu[LDS_DW];
    const int tid = threadIdx.x;
    const int plane0 = blockIdx.x * PPB;   // NPLANES % PPB == 0 -> no tail

    // ---- Stage x: unit = (plane, row, half-row of 16 floats) -> 8 packed dwords ----
#pragma unroll
    for (int it = 0; it < 2; ++it) {
        const int u    = tid + it * 128;   // PPB*64 = 256 units
        const int pl   = u >> 6;
        const int rh   = u & 63;
        const int row  = rh >> 1;
        const int half = rh & 1;
        const float* g = x + (size_t)(plane0 + pl) * 1024 + row * 32 + half * 16;
        const float4 v0 = *reinterpret_cast<const float4*>(g + 0);
        const float4 v1 = *reinterpret_cast<const float4*>(g + 4);
        const float4 v2 = *reinterpret_cast<const float4*>(g + 8);
        const float4 v3 = *reinterpret_cast<const float4*>(g + 12);
        unsigned A[8];
        A[0] = cvt_pk_bf16(v0.x, v0.y); A[1] = cvt_pk_bf16(v0.z, v0.w);
        A[2] = cvt_pk_bf16(v1.x, v1.y); A[3] = cvt_pk_bf16(v1.z, v1.w);
        A[4] = cvt_pk_bf16(v2.x, v2.y); A[5] = cvt_pk_bf16(v2.z, v2.w);
        A[6] = cvt_pk_bf16(v3.x, v3.y); A[7] = cvt_pk_bf16(v3.z, v3.w);
        unsigned* base = &ldsu[pl * XP + plane_shift(pl) + row * RST + half * 8];
        *reinterpret_cast<uint2*>(base + 0) = make_uint2(A[0], A[1]);
        *reinterpret_cast<uint2*>(base + 2) = make_uint2(A[2], A[3]);
        *reinterpret_cast<uint2*>(base + 4) = make_uint2(A[4], A[5]);
        *reinterpret_cast<uint2*>(base + 6) = make_uint2(A[6], A[7]);
    }
    // ---- Stage taps: PPB*16 = 64 units ----
    if (tid < PPB * 16) {
        const int pl = tid >> 4;
        const int o4 = tid & 15;
        const float4 v =
            *reinterpret_cast<const float4*>(kern + (size_t)(plane0 + pl) * 64 + o4 * 4);
        unsigned* kb = &ldsu[KTB + pl * KTS + o4 * 2];
        kb[0] = cvt_pk_bf16(v.x, v.y);
        kb[1] = cvt_pk_bf16(v.z, v.w);
    }
    __syncthreads();

    const int pb = tid / 25;
    if (pb >= PPB) return;           // tids 100..127 idle after staging
    const int ox = tid % 25;

    // ---- Taps -> 32 packed dwords (register-resident) ----
    unsigned kt[32];
    {
        const unsigned* kp = &ldsu[KTB + pb * KTS];
#pragma unroll
        for (int i = 0; i < 8; ++i) {
            const uint4 q = *reinterpret_cast<const uint4*>(kp + 4 * i);
            kt[4*i+0] = q.x; kt[4*i+1] = q.y; kt[4*i+2] = q.z; kt[4*i+3] = q.w;
        }
    }

    float acc[OH];
#pragma unroll
    for (int i = 0; i < OH; ++i) acc[i] = 0.f;

    // Window: 5 dwords (pairs p0..p0+4), shifted by (ox&1)*16 bits in-register.
    const unsigned sh = (ox & 1) * 16;
    const unsigned* xb = &ldsu[pb * XP + plane_shift(pb) + (ox >> 1)];
#pragma unroll
    for (int r = 0; r < 32; ++r) {
        const unsigned* rp = xb + r * RST;
        const unsigned d0 = rp[0], d1 = rp[1], d2 = rp[2], d3 = rp[3], d4 = rp[4];
        const unsigned w0 = alignb(d1, d0, sh);
        const unsigned w1 = alignb(d2, d1, sh);
        const unsigned w2 = alignb(d3, d2, sh);
        const unsigned w3 = alignb(d4, d3, sh);
#pragma unroll
        for (int ky = 0; ky < 8; ++ky) {
            const int oy = r - ky;               // compile-time with full unroll
            if (oy >= 0 && oy < OH) {
                dot2(acc[oy], w0, kt[ky * 4 + 0]);
                dot2(acc[oy], w1, kt[ky * 4 + 1]);
                dot2(acc[oy], w2, kt[ky * 4 + 2]);
                dot2(acc[oy], w3, kt[ky * 4 + 3]);
            }
        }
    }

    // ---- Coalesced stores: consecutive ox lanes -> consecutive addresses ----
    float* op = out + (size_t)(plane0 + pb) * (OH * OW) + ox;
#pragma unroll
    for (int oy = 0; oy < OH; ++oy) op[oy * OW] = acc[oy];
}

extern "C" void kernel_launch(void* const* d_in, const int* in_sizes, int n_in,
                              void* d_out, int out_size, void* d_ws, size_t ws_size,
                              hipStream_t stream) {
    const float* x = (const float*)d_in[0];
    const float* k = (const float*)d_in[1];
    // d_in[2] (weight) unused: softmax weights sum to exactly 1.
    float* out = (float*)d_out;
    const int nblocks = NPLANES / PPB;   // 8192
    dwxcorr_kernel<<<nblocks, 128, 0, stream>>>(x, k, out);
}